// Round 16
// baseline (2280.308 us; speedup 1.0000x reference)
//
#include <hip/hip_runtime.h>
#include <cstdint>
#include <cstddef>

// ---------------------------------------------------------------------------
// ConditionedPNA on MI355X, round 32 = R31 (2.23 ms, best) with two
// integer-exact selection-pipeline cuts:
//  (1) k_indegW persists per-wave src-selected ballots into the dead ELIST
//      region (25000 waves x 2 u32; ELIST written only later by
//      selEdgesCompact). k_countEq(mode=1) derives ssel from the ballot ->
//      drops the 6.4MB esrc stream + 1.6M nsel gathers; edst/score loads
//      predicated on ssel. k==original (KEY_NEG_INF when !ssel) -> bit-exact.
//  (2) all 3 scan dispatches removed: selNodes/rowSnap inline-sum their <=48
//      preceding block counts; selEdgesCompact computes eBase/gBase/gtTot by
//      one masked block-reduction over the 1563 raw counts (and writes
//      st[2]/st[4] from block 0). Same integer values -> same ranks.
// aggpna/scoreK verbatim from R30/R31.
// NOTE: all atomics use pointer-arithmetic form (arr + i) -- the source
// pipeline HTML-decodes "&"+identifier sequences.
// ---------------------------------------------------------------------------

#define NN   50000
#define NEG  1600000
#define NR2  1000
#define NTC  32
#define NMI  10000
#define KSEL 5000u
#define ESEL 160000u
#define KEY_NEG_INF 0x007FFFFFu
#define NEBK 1563                                // edge blocks (1024 threads)
#define NWAVE_E (NEG/64)                         // 25000 edge waves

// per-batch workspace block offsets (u32 units)
#define OFF_ST    0         // 64   (st[0]=v st[1]=R st[2]=takeTot st[3]=nact st[4]=gtTot st[5]=srcCnt, stF[7]=head)
#define OFF_RELB  64        // 64
#define OFF_BC    128       // 2048
#define OFF_BC2   2176      // 2048
#define OFF_HISTA 4224      // 65536 (pass1)
#define OFF_HISTB 69760     // 65536 (pass0)  [A+B contiguous 131072]
#define OFF_SCORE 135296    // 50000
#define OFF_NSEL  185296    // 50000 (0/1 from selNodes; slot map after rowSnap)
#define OFF_DCNT  235296    // 50000
#define OFF_ROWS  285296    // 50000
#define OFF_CURS  335296    // 50000 (indeg during edge select; csr cursor after)
#define OFF_ACT   385296    // 50000
#define OFF_HID   435296    // 3200000
#define OFF_SRCH  3635296   // 320000 (source snapshot)
#define OFF_ELIST 3955296   // 160000 (srcsel ballots during edge select; edge list after)
#define OFF_CSR   4115296   // 160000 (eq/gt ballots during edge select; packed csr after scatter)
#define OFF_BALG  (OFF_CSR + 50032)             // gbal half (25008 x 2 u32)
#define SBLK      4275296

#define RL(x,k) __int_as_float(__builtin_amdgcn_readlane(__float_as_int(x),(k)))
#define BBASE unsigned* B = WB + (size_t)blockIdx.y * (size_t)sb

__device__ inline unsigned fkey(float f){
  unsigned u = __float_as_uint(f);
  if ((u << 1) == 0u) u = 0u;                    // canonicalize -0 -> +0
  return (u & 0x80000000u) ? ~u : (u | 0x80000000u);
}

__device__ inline float waveSumF(float v){
  #pragma unroll
  for (int d = 1; d < 64; d <<= 1) v += __shfl_xor(v, d);
  return v;
}

__device__ inline void ldsHashAdd(unsigned* hkey, unsigned* hval, unsigned bin, unsigned cnt){
  unsigned h = (bin * 2654435761u) >> 23;        // 9 bits -> 0..511
  while (true){
    unsigned prev = atomicCAS(hkey + h, 0xFFFFFFFFu, bin);
    if (prev == 0xFFFFFFFFu || prev == bin){ atomicAdd(hval + h, cnt); return; }
    h = (h + 1u) & 511u;
  }
}

// ------------------------------- setup kernels ------------------------------

__global__ void k_lastm(const int* __restrict__ all_index, int* __restrict__ lastm){
  int i = blockIdx.x * 256 + threadIdx.x;
  if (i < NMI) atomicMax(lastm + all_index[i], i);
}

__global__ void k_degfull(const int* __restrict__ esrc, unsigned* __restrict__ degf){
  int i = blockIdx.x * 256 + threadIdx.x;
  if (i < NEG) atomicAdd(degf + esrc[i], 1u);
}

// dmean accumulation: per-wave f32 atomicAdd, hardware order (validated)
__global__ void k_dsum(const unsigned* __restrict__ degf, float* __restrict__ gstF){
  int i = blockIdx.x * 256 + threadIdx.x;
  float v = (i < NN) ? logf((float)degf[i] + 1.f) : 0.f;
  v = waveSumF(v);
  if ((threadIdx.x & 63) == 0) atomicAdd(gstF + 4, v);
}

__global__ void k_finalize(float* __restrict__ gstF, const float* __restrict__ b1,
                           const float* __restrict__ w2, const float* __restrict__ b2){
  gstF[5] = gstF[4] / (float)NN;                // dmean
  float s = 0.f;
  for (int m = 0; m < 128; m++) s += fmaxf(b1[m], 0.f) * w2[m];
  gstF[6] = s + b2[0];                          // base score for zero hidden
}

// ----------------------------- per-batch init -------------------------------

__global__ void k_relb(unsigned* WB, long sb, int b0,
                       const int* __restrict__ r_index, const float* __restrict__ hs,
                       const float* __restrict__ rel_table, const float* __restrict__ lw,
                       const float* __restrict__ lb, const float* __restrict__ w1,
                       const float* __restrict__ b1, const float* __restrict__ w2,
                       const float* __restrict__ b2){
  BBASE;
  float* relb = (float*)(B + OFF_RELB);
  float* stF  = (float*)(B + OFF_ST);
  int b = b0 + blockIdx.y;
  int j = threadIdx.x;                          // 64 threads, 1 wave
  int r = r_index[b];
  float acc = lb[j];
  for (int k = 0; k < 64; k++) acc = fmaf(rel_table[(size_t)r*64 + k], lw[(64 + k)*64 + j], acc);
  relb[j] = acc;
  float heur = acc;
  for (int k = 0; k < 64; k++) heur = fmaf(hs[b*64 + k], lw[k*64 + j], heur);
  float x = hs[b*64 + j] * heur;
  float o = 0.f;
  for (int half = 0; half < 2; half++){
    float a = b1[half*64 + j];
    for (int k = 0; k < 64; k++) a = fmaf(__shfl(x, k), w1[k*128 + half*64 + j], a);
    o = fmaf(fmaxf(a, 0.f), w2[half*64 + j], o);
  }
  o = waveSumF(o);
  if (j == 0) stF[7] = o + b2[0];
}

__global__ void k_inithidden(unsigned* WB, long sb, int b0,
                             const int* __restrict__ lastm, const float* __restrict__ ste,
                             const float* __restrict__ hs, const int* __restrict__ h_index){
  BBASE;
  float4* hidden = (float4*)(B + OFF_HID);
  const float4* ste4 = (const float4*)ste;
  const float4* hs4  = (const float4*)hs;
  int b = b0 + blockIdx.y;
  int idx = blockIdx.x * 256 + threadIdx.x;     // grid covers NN*16 exactly
  int n = idx >> 4, j = idx & 15;
  int h = h_index[b];
  float4 v = make_float4(0.f, 0.f, 0.f, 0.f);
  int lm = lastm[n];
  if (lm >= 0) v = ste4[(size_t)lm*16 + j];
  if (n == h)  v = hs4[b*16 + j];
  hidden[idx] = v;
}

__global__ void k_initscore(unsigned* WB, long sb, int b0,
                            const int* __restrict__ h_index, const float* __restrict__ gstF){
  BBASE;
  float* score = (float*)(B + OFF_SCORE);
  unsigned* st = B + OFF_ST;
  float* stF = (float*)st;
  int b = b0 + blockIdx.y;
  int i = blockIdx.x * 256 + threadIdx.x;
  if (i < NN) score[i] = (i == h_index[b]) ? stF[7] : gstF[6];
  if (i == 0){ st[0] = 0u; st[1] = KSEL; }
}

// ------------------------------ top-k machinery -----------------------------

// node histogram (unweighted): 2 leader rounds -> LDS hash -> single-plane flush
__global__ __launch_bounds__(256) void k_hist(unsigned* WB, long sb, int pass){
  BBASE;
  const unsigned* st = B + OFF_ST;
  const float* score = (const float*)(B + OFF_SCORE);
  unsigned* hist = B + ((pass == 1) ? OFF_HISTA : OFF_HISTB);
  __shared__ unsigned hkey[512];
  __shared__ unsigned hval[512];
  for (int t = threadIdx.x; t < 512; t += 256){ hkey[t] = 0xFFFFFFFFu; hval[t] = 0u; }
  __syncthreads();
  int i = blockIdx.x * 256 + threadIdx.x;
  unsigned bin = 0xFFFFFFFFu;
  if (i < NN){
    unsigned k = fkey(score[i]);
    if (pass == 1) bin = k >> 16;
    else if ((k >> 16) == (st[0] >> 16)) bin = k & 0xFFFFu;
  }
  bool active = (bin != 0xFFFFFFFFu);
  int lane = threadIdx.x & 63;
  #pragma unroll
  for (int r = 0; r < 2; r++){
    unsigned long long mask = __ballot((int)active);
    if (mask != 0ull){
      int leader = __ffsll(mask) - 1;
      unsigned lbin = (unsigned)__shfl((int)bin, leader);
      bool same = active && (bin == lbin);
      unsigned long long smask = __ballot((int)same);
      if (lane == leader) ldsHashAdd(hkey, hval, lbin, (unsigned)__popcll(smask));
      if (same) active = false;
    }
  }
  if (active) ldsHashAdd(hkey, hval, bin, 1u);
  __syncthreads();
  for (int t = threadIdx.x; t < 512; t += 256){
    unsigned vv = hval[t];
    if (vv) atomicAdd(hist + hkey[t], vv);
  }
}

// in-degree (from selected sources) accumulation into CURS + st reset;
// R32: persists per-wave src-selected ballots into the dead ELIST region.
__global__ void k_indegW(unsigned* WB, long sb,
                         const int* __restrict__ esrc, const int* __restrict__ edst){
  BBASE;
  unsigned* st = B + OFF_ST;
  const unsigned* nsel = B + OFF_NSEL;
  unsigned* indeg = B + OFF_CURS;
  unsigned* sbal = B + OFF_ELIST;                // dead until selEdgesCompact
  int i = blockIdx.x * 256 + threadIdx.x;       // grid covers NEG exactly
  int wid = threadIdx.x >> 6, lane = threadIdx.x & 63;
  bool s = nsel[esrc[i]] != 0u;
  unsigned long long bal = __ballot((int)s);
  if (s) atomicAdd(indeg + edst[i], 1u);
  if (lane == 0){
    int gw = blockIdx.x * 4 + wid;
    sbal[2*gw]     = (unsigned)bal;
    sbal[2*gw + 1] = (unsigned)(bal >> 32);
  }
  if (i == 0){ st[0] = 0u; st[1] = ESEL; st[2] = 0u; st[3] = 0u; st[4] = 0u; st[5] = 0u; }
}

// weighted node histogram for the edge top-ESEL (weight = indeg)
__global__ __launch_bounds__(256) void k_histW(unsigned* WB, long sb, int pass){
  BBASE;
  const unsigned* st = B + OFF_ST;
  const unsigned* indeg = B + OFF_CURS;
  const float* score = (const float*)(B + OFF_SCORE);
  unsigned* hist = B + ((pass == 1) ? OFF_HISTA : OFF_HISTB);
  __shared__ unsigned hkey[512];
  __shared__ unsigned hval[512];
  for (int t = threadIdx.x; t < 512; t += 256){ hkey[t] = 0xFFFFFFFFu; hval[t] = 0u; }
  __syncthreads();
  int i = blockIdx.x * 256 + threadIdx.x;
  unsigned w = (i < NN) ? indeg[i] : 0u;
  if (w){
    unsigned k = fkey(score[i]);
    unsigned bin = 0xFFFFFFFFu;
    if (pass == 1) bin = k >> 16;
    else if ((k >> 16) == (st[0] >> 16)) bin = k & 0xFFFFu;
    if (bin != 0xFFFFFFFFu) ldsHashAdd(hkey, hval, bin, w);
  }
  __syncthreads();
  for (int t = threadIdx.x; t < 512; t += 256){
    unsigned vv = hval[t];
    if (vv) atomicAdd(hist + hkey[t], vv);
  }
}

// single block per batch: find digit containing the R-th largest; update st.
__global__ __launch_bounds__(1024) void k_pick16(unsigned* WB, long sb, int pass){
  BBASE;
  unsigned* st = B + OFF_ST;
  const unsigned* hist = B + ((pass == 1) ? OFF_HISTA : OFF_HISTB);
  __shared__ unsigned csum[1024];
  __shared__ unsigned sc[1024];
  int t = threadIdx.x;
  unsigned R = st[1];
  unsigned s = 0;
  {
    const unsigned* hp = hist + (unsigned)t * 64u;
    for (int b = 0; b < 64; b++) s += hp[b];
  }
  csum[t] = s; sc[t] = s; __syncthreads();
  for (int d = 1; d < 1024; d <<= 1){
    unsigned v = (t >= d) ? sc[t - d] : 0u;
    __syncthreads();
    sc[t] += v;
    __syncthreads();
  }
  unsigned total = sc[1023];
  unsigned above = total - sc[t];               // keys in higher chunks
  unsigned cs = csum[t];
  if (above < R && above + cs >= R){
    unsigned cum = above;
    for (int b = 63; b >= 0; b--){
      unsigned c = hist[(unsigned)(t*64 + b)];
      if (cum + c >= R){
        unsigned bstar = (unsigned)(t*64 + b);
        if (pass == 1) st[0] = bstar << 16; else st[0] = st[0] | bstar;
        st[1] = R - cum;
        break;
      }
      cum += c;
    }
  }
  if (t == 0 && total < R){                     // threshold lands in -inf bin
    if (pass == 1) st[0] = KEY_NEG_INF & 0xFFFF0000u;
    else           st[0] = st[0] | 0xFFFFu;
    st[1] = R - total;
  }
}

// per-block counts of (eq, gt) vs threshold; zeroes hist buffers AND dcnt.
// mode 0: node keys. mode 1: edge keys via srcsel ballots + ballots saved.
// Block counts stored RAW (consumers compute their own prefixes).
__global__ __launch_bounds__(1024) void k_countEq(unsigned* WB, long sb, int mode, int n,
                                                  const int* __restrict__ esrc,
                                                  const int* __restrict__ edst){
  BBASE;
  unsigned* hz = B + OFF_HISTA;                  // A+B contiguous: 131072 u32
  for (unsigned j = blockIdx.x * 1024u + threadIdx.x; j < 131072u; j += gridDim.x * 1024u)
    hz[j] = 0u;
  unsigned* dcnt = B + OFF_DCNT;
  const unsigned* st = B + OFF_ST;
  const float* score = (const float*)(B + OFF_SCORE);
  unsigned* bcE = B + OFF_BC;
  unsigned* bcG = B + OFF_BC2;
  unsigned* balE = B + OFF_CSR;                  // eq/gt ballots (CSR dead here)
  unsigned* balG = B + OFF_BALG;
  int i = blockIdx.x * 1024 + threadIdx.x;
  if (i < NN) dcnt[i] = 0u;
  unsigned v = st[0];
  int wid = threadIdx.x >> 6, lane = threadIdx.x & 63;
  bool eq = false, gt = false;
  if (mode){
    const unsigned* sbal = B + OFF_ELIST;        // srcsel ballots from indegW
    int gw = blockIdx.x * 16 + wid;
    if (gw < NWAVE_E){
      unsigned long long sb64 = ((unsigned long long)sbal[2*gw + 1] << 32) | sbal[2*gw];
      bool ssel = (sb64 >> lane) & 1ull;
      unsigned k = KEY_NEG_INF;
      if (ssel) k = fkey(score[edst[i]]);
      eq = (k == v);
      gt = (k > v);
    }
  } else {
    unsigned k = 0u;
    if (i < n) k = fkey(score[i]);
    eq = (i < n) && (k == v);
    gt = (i < n) && (k > v);
  }
  unsigned long long ebal = __ballot((int)eq);
  unsigned long long gbal = __ballot((int)gt);
  __shared__ unsigned wshE[16];
  __shared__ unsigned wshG[16];
  if (mode && lane == 0){                        // persist ballots for compaction
    int gw = blockIdx.x * 16 + wid;
    balE[2*gw]     = (unsigned)ebal;
    balE[2*gw + 1] = (unsigned)(ebal >> 32);
    balG[2*gw]     = (unsigned)gbal;
    balG[2*gw + 1] = (unsigned)(gbal >> 32);
  }
  if (lane == 0){ wshE[wid] = (unsigned)__popcll(ebal); wshG[wid] = (unsigned)__popcll(gbal); }
  __syncthreads();
  if (threadIdx.x == 0){
    unsigned te = 0, tg = 0;
    for (int w = 0; w < 16; w++){ te += wshE[w]; tg += wshG[w]; }
    bcE[blockIdx.x] = te; bcG[blockIdx.x] = tg;
  }
}

// node selection; also zeroes CURS (used as indeg accumulator next).
// R32: computes its own block prefix from RAW bcE counts (<=48 adds).
__global__ __launch_bounds__(1024) void k_selNodes(unsigned* WB, long sb){
  BBASE;
  const unsigned* st = B + OFF_ST;
  const unsigned* blockcnt = B + OFF_BC;
  const float* score = (const float*)(B + OFF_SCORE);
  unsigned* nsel = B + OFF_NSEL;
  unsigned* curs = B + OFF_CURS;
  int i = blockIdx.x * 1024 + threadIdx.x;
  if (i < NN) curs[i] = 0u;
  unsigned v = st[0], R = st[1];
  unsigned k = (i < NN) ? fkey(score[i]) : 0u;
  bool eq = (i < NN) && (k == v);
  unsigned long long bal = __ballot((int)eq);
  __shared__ unsigned wsh[16];
  int wid = threadIdx.x >> 6, lane = threadIdx.x & 63;
  if (lane == 0) wsh[wid] = (unsigned)__popcll(bal);
  __syncthreads();
  unsigned pre = 0;
  for (int bn = 0; bn < blockIdx.x; bn++) pre += blockcnt[bn];
  unsigned woff = 0;
  for (int w = 0; w < wid; w++) woff += wsh[w];
  unsigned lpre = (unsigned)__popcll(bal & ((1ull << lane) - 1ull));
  unsigned rank = pre + woff + lpre;
  if (i < NN) nsel[i] = (k > v || (eq && rank < R)) ? 1u : 0u;
}

// ballot-driven edge compaction (keys from stored ballots; deterministic);
// R32: block-reduction over RAW bcE/bcG replaces scanBlocks2 (also writes
// st[2]/st[4] from block 0). accumulates dcnt[dst] for taken edges.
__global__ __launch_bounds__(1024) void k_selEdgesCompact(unsigned* WB, long sb,
                                                          const int* __restrict__ esrc,
                                                          const int* __restrict__ edst){
  BBASE;
  unsigned* st = B + OFF_ST;
  const unsigned* bcE = B + OFF_BC;
  const unsigned* bcG = B + OFF_BC2;
  const unsigned* balE = B + OFF_CSR;
  const unsigned* balG = B + OFF_BALG;
  unsigned* elist = B + OFF_ELIST;
  unsigned* dcnt = B + OFF_DCNT;
  int i = blockIdx.x * 1024 + threadIdx.x;
  unsigned v = st[0], R = st[1];
  int t = threadIdx.x;
  int wid = threadIdx.x >> 6, lane = threadIdx.x & 63;
  int gw = blockIdx.x * 16 + wid;
  unsigned long long ebal = ((unsigned long long)balE[2*gw + 1] << 32) | balE[2*gw];
  unsigned long long gbal = ((unsigned long long)balG[2*gw + 1] << 32) | balG[2*gw];
  bool eq = (ebal >> lane) & 1ull;
  bool gt = (gbal >> lane) & 1ull;
  // ---- masked block reduction: prefix (t < bid) and total (t < NEBK)
  unsigned eP = 0, gP = 0, gT = 0;
  if (t < blockIdx.x){ eP = bcE[t]; gP = bcG[t]; }
  if (1024 + t < blockIdx.x){ eP += bcE[1024 + t]; gP += bcG[1024 + t]; }
  if (t < NEBK) gT = bcG[t];
  if (1024 + t < NEBK) gT += bcG[1024 + t];
  #pragma unroll
  for (int d = 1; d < 64; d <<= 1){
    eP += (unsigned)__shfl_xor((int)eP, d);
    gP += (unsigned)__shfl_xor((int)gP, d);
    gT += (unsigned)__shfl_xor((int)gT, d);
  }
  __shared__ unsigned wE[16], wG[16], wT[16], wshE[16], wshG[16];
  if (lane == 0){
    wE[wid] = eP; wG[wid] = gP; wT[wid] = gT;
    wshE[wid] = (unsigned)__popcll(ebal); wshG[wid] = (unsigned)__popcll(gbal);
  }
  __syncthreads();
  unsigned eBase = 0, gBase = 0, gtTot = 0;
  for (int w = 0; w < 16; w++){ eBase += wE[w]; gBase += wG[w]; gtTot += wT[w]; }
  unsigned eoff = 0, goff = 0;
  for (int w = 0; w < wid; w++){ eoff += wshE[w]; goff += wshG[w]; }
  if (blockIdx.x == 0 && threadIdx.x == 0){
    st[4] = gtTot;
    st[2] = gtTot + ((v > KEY_NEG_INF) ? R : 0u);   // R' <= eqTot always
  }
  unsigned long long ltm = (1ull << lane) - 1ull;
  if (gt){
    elist[gBase + goff + (unsigned)__popcll(gbal & ltm)] = (unsigned)i;
    atomicAdd(dcnt + edst[i], 1u);
  }
  if (eq){
    unsigned rank = eBase + eoff + (unsigned)__popcll(ebal & ltm);
    if (v > KEY_NEG_INF && rank < R){
      elist[gtTot + rank] = (unsigned)i;
      atomicAdd(dcnt + edst[i], 1u);
    }
  }
}

// ------------------------------- CSR build ----------------------------------

__global__ __launch_bounds__(1024) void k_blocksumsInt(unsigned* WB, long sb){
  BBASE;
  const unsigned* dcnt = B + OFF_DCNT;
  unsigned* blockcnt = B + OFF_BC;
  int i = blockIdx.x * 1024 + threadIdx.x;
  unsigned v = (i < NN) ? dcnt[i] : 0u;
  #pragma unroll
  for (int d = 1; d < 64; d <<= 1) v += (unsigned)__shfl_xor((int)v, d);
  __shared__ unsigned wsh[16];
  int wid = threadIdx.x >> 6, lane = threadIdx.x & 63;
  if (lane == 0) wsh[wid] = v;
  __syncthreads();
  if (threadIdx.x == 0){
    unsigned tot = 0;
    for (int w = 0; w < 16; w++) tot += wsh[w];
    blockcnt[blockIdx.x] = tot;
  }
}

// row starts + cursor + ACTIVE list + source snapshot (merged).
// R32: computes its own block prefix from RAW blockcnt (<=48 adds).
__global__ __launch_bounds__(1024) void k_rowSnap(unsigned* WB, long sb){
  BBASE;
  unsigned* st = B + OFF_ST;
  const unsigned* dcnt = B + OFF_DCNT;
  const unsigned* blockcnt = B + OFF_BC;
  unsigned* rowstart = B + OFF_ROWS;
  unsigned* curs = B + OFF_CURS;
  unsigned* actl = B + OFF_ACT;
  unsigned* srcmap = B + OFF_NSEL;
  const float* score = (const float*)(B + OFF_SCORE);
  const float* hidden = (const float*)(B + OFF_HID);
  float* srch = (float*)(B + OFF_SRCH);
  int i = blockIdx.x * 1024 + threadIdx.x;
  int wid = threadIdx.x >> 6, lane = threadIdx.x & 63;
  unsigned d = (i < NN) ? dcnt[i] : 0u;
  unsigned v = d;
  #pragma unroll
  for (int dl = 1; dl < 64; dl <<= 1){
    unsigned t2 = (unsigned)__shfl_up((int)v, dl);
    if (lane >= dl) v += t2;
  }
  bool act = (i < NN) && (d > 0u);
  unsigned long long abal = __ballot((int)act);
  __shared__ unsigned wsh[16];
  __shared__ unsigned awsh[16];
  __shared__ unsigned abase;
  if (lane == 63) wsh[wid] = v;
  if (lane == 0) awsh[wid] = (unsigned)__popcll(abal);
  __syncthreads();
  if (threadIdx.x == 0){
    unsigned tot = 0;
    for (int w = 0; w < 16; w++) tot += awsh[w];
    abase = atomicAdd(st + 3, tot);
  }
  unsigned pre = 0;
  for (int bn = 0; bn < blockIdx.x; bn++) pre += blockcnt[bn];
  unsigned woff = 0, aoff = 0;
  for (int w = 0; w < wid; w++){ woff += wsh[w]; aoff += awsh[w]; }
  __syncthreads();
  unsigned excl = pre + woff + (v - d);
  if (i < NN){ rowstart[i] = excl; curs[i] = excl; }
  if (act) actl[abase + aoff + (unsigned)__popcll(abal & ((1ull << lane) - 1ull))] = (unsigned)i;

  // ---- snap part: each wave handles its 64 nodes (disjoint arrays above)
  int base = i - lane;                        // wave's node base
  if (base >= NN) return;
  bool sel = (i < NN) && (srcmap[i] != 0u);
  unsigned long long bal = __ballot((int)sel);
  if (bal == 0ull) return;
  unsigned slotbase = 0;
  if (lane == 0) slotbase = atomicAdd(st + 5, (unsigned)__popcll(bal));
  slotbase = (unsigned)__shfl((int)slotbase, 0);
  unsigned long long m2 = bal;
  unsigned idx = 0;
  while (m2){
    int j = __ffsll(m2) - 1;
    m2 = m2 - (m2 bitand (0ull - m2));        // clear lowest set bit (entity-safe)
    int node = base + j;
    unsigned slot = slotbase + idx; idx++;
    if (lane == 0) srcmap[node] = slot;
    float g = 1.f / (1.f + expf(-score[node]));   // same formula as before
    srch[(size_t)slot*64 + lane] = g * hidden[(size_t)node*64 + lane];
  }
}

// scatter packed (slot<<10)|etype into CSR (needs srcmap from k_rowSnap)
__global__ void k_scatter(unsigned* WB, long sb, const int* __restrict__ esrc,
                          const int* __restrict__ edst, const int* __restrict__ etype){
  BBASE;
  const unsigned* st = B + OFF_ST;
  const unsigned* elist = B + OFF_ELIST;
  const unsigned* srcmap = B + OFF_NSEL;
  unsigned* curs = B + OFF_CURS;
  unsigned* csr = B + OFF_CSR;
  unsigned i = blockIdx.x * 256 + threadIdx.x;
  if (i < st[2]){
    unsigned e = elist[i];
    unsigned slot = srcmap[esrc[e]];
    unsigned pk = (slot << 10) | (unsigned)etype[e];
    unsigned pos = atomicAdd(curs + edst[e], 1u);
    csr[pos] = pk;
  }
}

// --------------------- fused aggregation + PNA update -----------------------
// R30 aggpna (unchanged): lane=node + SGPR-weight matmul; 16 KB LDS single
// plane; single gather with bulk metadata prefetch + group-of-4 first-chunk
// csr prefetch. Bit-exact.

__global__ __launch_bounds__(256) void k_aggpna(unsigned* WB, long sb,
    const float* __restrict__ relw, const float* __restrict__ pw,
    const float* __restrict__ pb, const float* __restrict__ gstF, int l){
  BBASE;
  const unsigned* st = B + OFF_ST;
  const unsigned* actl = B + OFF_ACT;
  const unsigned* dcnt = B + OFF_DCNT;
  const unsigned* rows = B + OFF_ROWS;
  const unsigned* csr = B + OFF_CSR;
  const float* srch = (const float*)(B + OFF_SRCH);
  float* hidden = (float*)(B + OFF_HID);
  const float* relw_l = relw + (size_t)l * NR2 * 64;
  const float* pw_l = pw + (size_t)l * 768 * 64;

  __shared__ float aggL[64 * 64];               // ONE plane, 16 KB

  int lane = threadIdx.x & 63;
  int w = threadIdx.x >> 6;
  unsigned nact = st[3];
  unsigned nbase = (unsigned)blockIdx.x * 64u;
  if (nbase >= nact) return;                    // block-uniform exit
  float dmean = gstF[5];

  // persistent matmul state (lane = node)
  unsigned slotM = nbase + (unsigned)lane;
  int nodeM = (slotM < nact) ? (int)actl[slotM] : -1;
  float dvM = (nodeM >= 0) ? (float)dcnt[nodeM] : 0.f;
  float logd = logf(dvM + 1.f);
  float ampv = logd / dmean;
  float attv = dmean / fmaxf(logd, 1e-6f);
  int jbase = __builtin_amdgcn_readfirstlane((int)(threadIdx.x >> 6)) * 16;
  float acc[16];
  #pragma unroll
  for (int jj = 0; jj < 16; jj++) acc[jj] = pb[(size_t)l*64 + jbase + jj];

  // ---- bulk metadata prefetch: the wave's 16 nodes (wave-uniform addrs)
  int nodeG[16]; unsigned cntG[16], rsG[16];
  #pragma unroll
  for (int i = 0; i < 16; i++){
    unsigned slot = nbase + (unsigned)(w * 16 + i);
    nodeG[i] = (slot < nact) ? (int)actl[slot] : -1;
  }
  #pragma unroll
  for (int i = 0; i < 16; i++){
    cntG[i] = (nodeG[i] >= 0) ? dcnt[nodeG[i]] : 0u;
    rsG[i]  = (nodeG[i] >= 0) ? rows[nodeG[i]] : 0u;
  }

  // ---- SINGLE gather pass, group-of-4 first-chunk prefetch.
  float mxS[16], mnS[16], sdS[16];
  #pragma unroll
  for (int g = 0; g < 4; g++){
    // prefetch first csr chunk (clamped, identical to ii=0 indices)
    unsigned pkA[4], pkB[4], pkC[4], pkD[4];
    #pragma unroll
    for (int q = 0; q < 4; q++){
      int i = g*4 + q;
      unsigned cnt = cntG[i], rs = rsG[i];
      bool vld = (nodeG[i] >= 0);
      unsigned c1 = (1u < cnt) ? 1u : 0u;
      unsigned c2 = (2u < cnt) ? 2u : 0u;
      unsigned c3 = (3u < cnt) ? 3u : 0u;
      pkA[q] = vld ? csr[rs]      : 0u;
      pkB[q] = vld ? csr[rs + c1] : 0u;
      pkC[q] = vld ? csr[rs + c2] : 0u;
      pkD[q] = vld ? csr[rs + c3] : 0u;
    }
    #pragma unroll
    for (int q = 0; q < 4; q++){
      int i = g*4 + q;
      int nloc = w * 16 + i;
      float pmean = 0.f;
      mxS[i] = 0.f; mnS[i] = 0.f; sdS[i] = 0.f;
      if (nodeG[i] >= 0){
        unsigned cnt = cntG[i], rs = rsG[i];
        float sm_ = 0.f, sq_ = 0.f;
        float mx_ = -__builtin_huge_valf(), mn_ = __builtin_huge_valf();
        // ---- chunk 0 from prefetch (guards == original ii=0 guards)
        {
          unsigned pk0 = pkA[q], pk1 = pkB[q], pk2 = pkC[q], pk3 = pkD[q];
          float s0 = srch[(size_t)(pk0 >> 10)*64 + lane];
          float r0 = relw_l[(size_t)(pk0 & 1023u)*64 + lane];
          float s1 = srch[(size_t)(pk1 >> 10)*64 + lane];
          float r1 = relw_l[(size_t)(pk1 & 1023u)*64 + lane];
          float s2 = srch[(size_t)(pk2 >> 10)*64 + lane];
          float r2 = relw_l[(size_t)(pk2 & 1023u)*64 + lane];
          float s3 = srch[(size_t)(pk3 >> 10)*64 + lane];
          float r3 = relw_l[(size_t)(pk3 & 1023u)*64 + lane];
          float m = s0 * r0;
          sm_ += m; sq_ = fmaf(m, m, sq_); mx_ = fmaxf(mx_, m); mn_ = fminf(mn_, m);
          if (1u < cnt){
            m = s1 * r1;
            sm_ += m; sq_ = fmaf(m, m, sq_); mx_ = fmaxf(mx_, m); mn_ = fminf(mn_, m);
          }
          if (2u < cnt){
            m = s2 * r2;
            sm_ += m; sq_ = fmaf(m, m, sq_); mx_ = fmaxf(mx_, m); mn_ = fminf(mn_, m);
          }
          if (3u < cnt){
            m = s3 * r3;
            sm_ += m; sq_ = fmaf(m, m, sq_); mx_ = fmaxf(mx_, m); mn_ = fminf(mn_, m);
          }
        }
        // ---- remaining chunks (rare: avg degree ~3.3)
        for (unsigned ii = 4; ii < cnt; ii += 4u){
          unsigned i1 = (ii + 1u < cnt) ? ii + 1u : ii;
          unsigned i2 = (ii + 2u < cnt) ? ii + 2u : ii;
          unsigned i3 = (ii + 3u < cnt) ? ii + 3u : ii;
          unsigned pk0 = csr[rs + ii];
          unsigned pk1 = csr[rs + i1];
          unsigned pk2 = csr[rs + i2];
          unsigned pk3 = csr[rs + i3];
          float s0 = srch[(size_t)(pk0 >> 10)*64 + lane];
          float r0 = relw_l[(size_t)(pk0 & 1023u)*64 + lane];
          float s1 = srch[(size_t)(pk1 >> 10)*64 + lane];
          float r1 = relw_l[(size_t)(pk1 & 1023u)*64 + lane];
          float s2 = srch[(size_t)(pk2 >> 10)*64 + lane];
          float r2 = relw_l[(size_t)(pk2 & 1023u)*64 + lane];
          float s3 = srch[(size_t)(pk3 >> 10)*64 + lane];
          float r3 = relw_l[(size_t)(pk3 & 1023u)*64 + lane];
          float m = s0 * r0;
          sm_ += m; sq_ = fmaf(m, m, sq_); mx_ = fmaxf(mx_, m); mn_ = fminf(mn_, m);
          if (ii + 1u < cnt){
            m = s1 * r1;
            sm_ += m; sq_ = fmaf(m, m, sq_); mx_ = fmaxf(mx_, m); mn_ = fminf(mn_, m);
          }
          if (ii + 2u < cnt){
            m = s2 * r2;
            sm_ += m; sq_ = fmaf(m, m, sq_); mx_ = fmaxf(mx_, m); mn_ = fminf(mn_, m);
          }
          if (ii + 3u < cnt){
            m = s3 * r3;
            sm_ += m; sq_ = fmaf(m, m, sq_); mx_ = fmaxf(mx_, m); mn_ = fminf(mn_, m);
          }
        }
        float dv = (float)cnt;
        float degc = fmaxf(dv, 1.f);
        float me = sm_ / degc;
        pmean = me;
        mxS[i] = mx_;
        mnS[i] = mn_;
        sdS[i] = sqrtf(fmaxf(sq_ / degc - me*me, 0.f) + 1e-6f);
      }
      aggL[lane*64 + (nloc ^ lane)] = pmean;    // XOR swizzle (2-way banks)
    }
  }

  for (int p = 0; p < 4; p++){
    if (p){
      __syncthreads();                          // prior phase's matmul reads done
      #pragma unroll
      for (int i = 0; i < 16; i++){
        int nloc = w * 16 + i;
        float v = (p == 1) ? mxS[i] : ((p == 2) ? mnS[i] : sdS[i]);
        aggL[lane*64 + (nloc ^ lane)] = v;
      }
    }
    __syncthreads();
    // ---- matmul: c = p*3 .. p*3+2 from the single plane
    for (int cc = 0; cc < 3; cc++){
      int c = p*3 + cc;
      float sc = (cc == 0) ? 1.f : ((cc == 1) ? ampv : attv);
      const float* wc = pw_l + (size_t)c*64*64 + jbase;   // uniform -> s_load
      #pragma unroll 4
      for (int k = 0; k < 64; k++){
        float fv = aggL[k*64 + (lane ^ k)] * sc;          // 2-way banks
        const float* wp = wc + (size_t)k*64;
        #pragma unroll
        for (int jj = 0; jj < 16; jj++)
          acc[jj] = fmaf(fv, wp[jj], acc[jj]);            // SGPR weight operand
      }
    }
  }
  if (nodeM >= 0){
    float* hp = hidden + (size_t)nodeM*64 + jbase;
    #pragma unroll
    for (int q = 0; q < 4; q++){
      float4 h = *(float4*)(hp + q*4);
      h.x += acc[q*4+0]; h.y += acc[q*4+1]; h.z += acc[q*4+2]; h.w += acc[q*4+3];
      *(float4*)(hp + q*4) = h;
    }
  }
}

// ------------------------- rescore active nodes -----------------------------
// R30 scoreK (unchanged): lane=node + SGPR-weight, node prefetch in G phase.

__global__ __launch_bounds__(256) void k_scoreK(unsigned* WB, long sb,
    const float* __restrict__ lw, const float* __restrict__ w1,
    const float* __restrict__ b1, const float* __restrict__ w2,
    const float* __restrict__ b2){
  BBASE;
  unsigned* st = B + OFF_ST;
  if (blockIdx.x == 0 && threadIdx.x == 0){ st[0] = 0u; st[1] = KSEL; }  // next node topk
  const unsigned* actl = B + OFF_ACT;
  const float* hidden = (const float*)(B + OFF_HID);
  const float* relb = (const float*)(B + OFF_RELB);
  float* score = (float*)(B + OFF_SCORE);

  __shared__ float P0[64 * 64];                 // H, later P (pre-combined out)
  __shared__ float P1[64 * 64];                 // X

  int lane = threadIdx.x & 63;
  int w = threadIdx.x >> 6;
  unsigned nact = st[3];
  unsigned nbase = (unsigned)blockIdx.x * 64u;
  if (nbase >= nact) return;                    // block-uniform exit

  // ---- G: node prefetch, then hidden tile -> H[k][n^k] (lane = k)
  int nodeG[16];
  #pragma unroll
  for (int i = 0; i < 16; i++){
    unsigned slot = nbase + (unsigned)(w * 16 + i);
    nodeG[i] = (slot < nact) ? (int)actl[slot] : -1;
  }
  #pragma unroll
  for (int i = 0; i < 16; i++){
    int nloc = w * 16 + i;
    float hv = (nodeG[i] >= 0) ? hidden[(size_t)nodeG[i]*64 + lane] : 0.f;
    P0[lane*64 + (nloc ^ lane)] = hv;
  }
  __syncthreads();

  // ---- P1 phase: lane = node; wave w owns j in [16w, 16w+16)
  int jb = __builtin_amdgcn_readfirstlane(w) * 16;
  float heur[16];
  #pragma unroll
  for (int i = 0; i < 16; i++) heur[i] = relb[jb + i];
  #pragma unroll 4
  for (int k = 0; k < 64; k++){
    float hk = P0[k*64 + (lane ^ k)];
    const float* lwk = lw + k*64 + jb;          // uniform -> s_load
    #pragma unroll
    for (int i = 0; i < 16; i++) heur[i] = fmaf(hk, lwk[i], heur[i]);
  }
  #pragma unroll
  for (int i = 0; i < 16; i++){
    int j = jb + i;
    float hj = P0[j*64 + (lane ^ j)];
    P1[j*64 + (lane ^ j)] = hj * heur[i];       // x = hid * heur
  }
  __syncthreads();                              // X complete; H reads done

  // ---- P2 phase: lane = node; wave w owns m in {jb..jb+15} u {64+jb..}
  float alo[16], ahi[16];
  #pragma unroll
  for (int mm = 0; mm < 16; mm++){ alo[mm] = b1[jb + mm]; ahi[mm] = b1[64 + jb + mm]; }
  #pragma unroll 4
  for (int j = 0; j < 64; j++){
    float xj = P1[j*64 + (lane ^ j)];
    const float* w1j = w1 + j*128;              // uniform -> s_load
    #pragma unroll
    for (int mm = 0; mm < 16; mm++){
      alo[mm] = fmaf(xj, w1j[jb + mm], alo[mm]);
      ahi[mm] = fmaf(xj, w1j[64 + jb + mm], ahi[mm]);
    }
  }
  // pre-combine in the ORIGINAL per-lane two-term order -> P rows jb..jb+15
  #pragma unroll
  for (int mm = 0; mm < 16; mm++){
    int j = jb + mm;
    float p = fmaf(fmaxf(alo[mm], 0.f), w2[j], 0.f);
    p = fmaf(fmaxf(ahi[mm], 0.f), w2[64 + j], p);
    P0[j*64 + (lane ^ j)] = p;
  }
  __syncthreads();

  // ---- P3 phase: lane = j; original balanced butterfly per node
  float b2v = b2[0];
  for (int i = 0; i < 16; i++){
    int nloc = w * 16 + i;
    unsigned slot = nbase + (unsigned)nloc;
    float p = P0[lane*64 + (nloc ^ lane)];
    float r = waveSumF(p);
    if (lane == 0 && slot < nact) score[(int)actl[slot]] = r + b2v;
  }
}

__global__ void k_out(unsigned* WB, long sb, int b0,
                      const int* __restrict__ t_index, float* __restrict__ out){
  BBASE;
  const float* score = (const float*)(B + OFF_SCORE);
  int b = b0 + blockIdx.y;
  int t = threadIdx.x;
  if (t < NTC) out[b*NTC + t] = score[t_index[b*NTC + t]];
}

// ------------------------------- launcher -----------------------------------

extern "C" void kernel_launch(void* const* d_in, const int* in_sizes, int n_in,
                              void* d_out, int out_size, void* d_ws, size_t ws_size,
                              hipStream_t stream){
  (void)in_sizes; (void)n_in; (void)out_size;
  const int*   h_index  = (const int*)d_in[0];
  const int*   r_index  = (const int*)d_in[1];
  const int*   t_index  = (const int*)d_in[2];
  const int*   all_idx  = (const int*)d_in[3];
  const int*   esrc     = (const int*)d_in[4];
  const int*   edst     = (const int*)d_in[5];
  const int*   etype    = (const int*)d_in[6];
  const float* hs       = (const float*)d_in[7];
  const float* ste      = (const float*)d_in[8];
  const float* rel_tab  = (const float*)d_in[9];
  const float* lw       = (const float*)d_in[10];
  const float* lb       = (const float*)d_in[11];
  const float* w1       = (const float*)d_in[12];
  const float* b1       = (const float*)d_in[13];
  const float* w2       = (const float*)d_in[14];
  const float* b2       = (const float*)d_in[15];
  const float* relw     = (const float*)d_in[16];
  const float* pna_w    = (const float*)d_in[17];
  const float* pna_b    = (const float*)d_in[18];
  float* out = (float*)d_out;

  unsigned* W = (unsigned*)d_ws;
  int*      LASTM = (int*)W;                    // 50000
  unsigned* DEGF  = W + 50000;                  // 50000
  float*    GSTF  = (float*)(W + 100000);       // 64
  unsigned* WB    = W + 100064;                 // batch blocks

  size_t needB = (size_t)(100064 + 4*(size_t)SBLK) * 4u;
  int nb; long sb; int nseq;
  if (ws_size >= needB){ nb = 4; sb = SBLK; nseq = 1; }
  else                 { nb = 1; sb = 0;    nseq = 4; }

  (void)hipMemsetAsync(W + 100000, 0, 64 * 4, stream);          // GSTF
  (void)hipMemsetAsync(LASTM, 0xFF, NN * 4, stream);
  (void)hipMemsetAsync(DEGF, 0, NN * 4, stream);
  for (int q = 0; q < nb; q++)
    (void)hipMemsetAsync(WB + (size_t)q*SBLK + OFF_HISTA, 0, 131072 * 4, stream);

  const int GB_E256  = (NEG + 255) / 256;       // 6250
  const int GB_N256  = (NN + 255) / 256;        // 196
  const int GB_N1024 = (NN + 1023) / 1024;      // 49
  const int GB_E1024 = (NEG + 1023) / 1024;     // 1563
  const int GB_H4    = (NN * 16) / 256;         // 3125 (float4 rows)
  const int GB_A2    = (NN + 63) / 64;          // 782 (64 nodes per WG)
  const int GB_ES    = (int)(ESEL / 256);       // 625

  k_lastm<<<(NMI + 255) / 256, 256, 0, stream>>>(all_idx, LASTM);
  k_degfull<<<GB_E256, 256, 0, stream>>>(esrc, DEGF);
  k_dsum<<<GB_N256, 256, 0, stream>>>(DEGF, GSTF);
  k_finalize<<<1, 1, 0, stream>>>(GSTF, b1, w2, b2);

  for (int q = 0; q < nseq; q++){
    int b0 = (nb == 4) ? 0 : q;
    k_relb<<<dim3(1, nb), 64, 0, stream>>>(WB, sb, b0, r_index, hs, rel_tab, lw, lb, w1, b1, w2, b2);
    k_inithidden<<<dim3(GB_H4, nb), 256, 0, stream>>>(WB, sb, b0, LASTM, ste, hs, h_index);
    k_initscore<<<dim3(GB_N256, nb), 256, 0, stream>>>(WB, sb, b0, h_index, GSTF);

    for (int l = 0; l < 3; l++){
      // ---- node top-K
      k_hist<<<dim3(GB_N256, nb), 256, 0, stream>>>(WB, sb, 1);
      k_pick16<<<dim3(1, nb), 1024, 0, stream>>>(WB, sb, 1);
      k_hist<<<dim3(GB_N256, nb), 256, 0, stream>>>(WB, sb, 0);
      k_pick16<<<dim3(1, nb), 1024, 0, stream>>>(WB, sb, 0);
      k_countEq<<<dim3(GB_N1024, nb), 1024, 0, stream>>>(WB, sb, 0, NN, esrc, edst);
      k_selNodes<<<dim3(GB_N1024, nb), 1024, 0, stream>>>(WB, sb);      // + zeroes CURS
      // ---- edge top-ESEL as weighted node top-k
      k_indegW<<<dim3(GB_E256, nb), 256, 0, stream>>>(WB, sb, esrc, edst);
      k_histW<<<dim3(GB_N256, nb), 256, 0, stream>>>(WB, sb, 1);
      k_pick16<<<dim3(1, nb), 1024, 0, stream>>>(WB, sb, 1);
      k_histW<<<dim3(GB_N256, nb), 256, 0, stream>>>(WB, sb, 0);
      k_pick16<<<dim3(1, nb), 1024, 0, stream>>>(WB, sb, 0);
      k_countEq<<<dim3(GB_E1024, nb), 1024, 0, stream>>>(WB, sb, 1, NEG, esrc, edst);
      k_selEdgesCompact<<<dim3(GB_E1024, nb), 1024, 0, stream>>>(WB, sb, esrc, edst);
      // ---- CSR rows + active compaction + snapshot (merged) + scatter
      k_blocksumsInt<<<dim3(GB_N1024, nb), 1024, 0, stream>>>(WB, sb);
      k_rowSnap<<<dim3(GB_N1024, nb), 1024, 0, stream>>>(WB, sb);
      k_scatter<<<dim3(GB_ES, nb), 256, 0, stream>>>(WB, sb, esrc, edst, etype);
      // ---- fused aggregate + PNA update, then rescore
      k_aggpna<<<dim3(GB_A2, nb), 256, 0, stream>>>(WB, sb, relw, pna_w, pna_b, GSTF, l);
      k_scoreK<<<dim3(GB_A2, nb), 256, 0, stream>>>(WB, sb, lw, w1, b1, w2, b2);
    }
    k_out<<<dim3(1, nb), 32, 0, stream>>>(WB, sb, b0, t_index, out);
  }
}

// Round 17
// 2183.695 us; speedup vs baseline: 1.0442x; 1.0442x over previous
//
#include <hip/hip_runtime.h>
#include <cstdint>
#include <cstddef>

// ---------------------------------------------------------------------------
// ConditionedPNA on MI355X, round 33 = R31 (2.23 ms, best) + ONLY the srcsel
// ballot extension from R32 (the scan-dispatch removal is REVERTED -- R32's
// per-block count reductions cost more than the 3 tiny scan dispatches they
// replaced; net -47us). k_indegW persists per-wave src-sel ballots into the
// dead ELIST region; k_countEq(mode=1) derives ssel from them (drops the
// 6.4MB esrc stream + 1.6M nsel gathers). Lifetimes: sbal(ELIST) written by
// indegW, read by countEq m1; selEdgesCompact overwrites ELIST only after
// consuming balE/balG from the CSR region. Integer-exact -> bit-exact.
// aggpna/scoreK verbatim from R30.
// NOTE: all atomics use pointer-arithmetic form (arr + i) -- the source
// pipeline HTML-decodes "&"+identifier sequences.
// ---------------------------------------------------------------------------

#define NN   50000
#define NEG  1600000
#define NR2  1000
#define NTC  32
#define NMI  10000
#define KSEL 5000u
#define ESEL 160000u
#define KEY_NEG_INF 0x007FFFFFu
#define NWAVE_E (NEG/64)                         // 25000 edge waves

// per-batch workspace block offsets (u32 units)
#define OFF_ST    0         // 64   (st[0]=v st[1]=R st[2]=takeTot st[3]=nact st[4]=gtTot st[5]=srcCnt, stF[7]=head)
#define OFF_RELB  64        // 64
#define OFF_BC    128       // 2048
#define OFF_BC2   2176      // 2048
#define OFF_HISTA 4224      // 65536 (pass1)
#define OFF_HISTB 69760     // 65536 (pass0)  [A+B contiguous 131072]
#define OFF_SCORE 135296    // 50000
#define OFF_NSEL  185296    // 50000 (0/1 from selNodes; slot map after rowSnap)
#define OFF_DCNT  235296    // 50000
#define OFF_ROWS  285296    // 50000
#define OFF_CURS  335296    // 50000 (indeg during edge select; csr cursor after)
#define OFF_ACT   385296    // 50000
#define OFF_HID   435296    // 3200000
#define OFF_SRCH  3635296   // 320000 (source snapshot)
#define OFF_ELIST 3955296   // 160000 (srcsel ballots during edge select; edge list after)
#define OFF_CSR   4115296   // 160000 (eq/gt ballots during edge select; packed csr after scatter)
#define OFF_BALG  (OFF_CSR + 50032)             // gbal half (25008 x 2 u32)
#define SBLK      4275296

#define RL(x,k) __int_as_float(__builtin_amdgcn_readlane(__float_as_int(x),(k)))
#define BBASE unsigned* B = WB + (size_t)blockIdx.y * (size_t)sb

__device__ inline unsigned fkey(float f){
  unsigned u = __float_as_uint(f);
  if ((u << 1) == 0u) u = 0u;                    // canonicalize -0 -> +0
  return (u & 0x80000000u) ? ~u : (u | 0x80000000u);
}

__device__ inline float waveSumF(float v){
  #pragma unroll
  for (int d = 1; d < 64; d <<= 1) v += __shfl_xor(v, d);
  return v;
}

__device__ inline void ldsHashAdd(unsigned* hkey, unsigned* hval, unsigned bin, unsigned cnt){
  unsigned h = (bin * 2654435761u) >> 23;        // 9 bits -> 0..511
  while (true){
    unsigned prev = atomicCAS(hkey + h, 0xFFFFFFFFu, bin);
    if (prev == 0xFFFFFFFFu || prev == bin){ atomicAdd(hval + h, cnt); return; }
    h = (h + 1u) & 511u;
  }
}

// ------------------------------- setup kernels ------------------------------

__global__ void k_lastm(const int* __restrict__ all_index, int* __restrict__ lastm){
  int i = blockIdx.x * 256 + threadIdx.x;
  if (i < NMI) atomicMax(lastm + all_index[i], i);
}

__global__ void k_degfull(const int* __restrict__ esrc, unsigned* __restrict__ degf){
  int i = blockIdx.x * 256 + threadIdx.x;
  if (i < NEG) atomicAdd(degf + esrc[i], 1u);
}

// dmean accumulation: per-wave f32 atomicAdd, hardware order (validated)
__global__ void k_dsum(const unsigned* __restrict__ degf, float* __restrict__ gstF){
  int i = blockIdx.x * 256 + threadIdx.x;
  float v = (i < NN) ? logf((float)degf[i] + 1.f) : 0.f;
  v = waveSumF(v);
  if ((threadIdx.x & 63) == 0) atomicAdd(gstF + 4, v);
}

__global__ void k_finalize(float* __restrict__ gstF, const float* __restrict__ b1,
                           const float* __restrict__ w2, const float* __restrict__ b2){
  gstF[5] = gstF[4] / (float)NN;                // dmean
  float s = 0.f;
  for (int m = 0; m < 128; m++) s += fmaxf(b1[m], 0.f) * w2[m];
  gstF[6] = s + b2[0];                          // base score for zero hidden
}

// ----------------------------- per-batch init -------------------------------

__global__ void k_relb(unsigned* WB, long sb, int b0,
                       const int* __restrict__ r_index, const float* __restrict__ hs,
                       const float* __restrict__ rel_table, const float* __restrict__ lw,
                       const float* __restrict__ lb, const float* __restrict__ w1,
                       const float* __restrict__ b1, const float* __restrict__ w2,
                       const float* __restrict__ b2){
  BBASE;
  float* relb = (float*)(B + OFF_RELB);
  float* stF  = (float*)(B + OFF_ST);
  int b = b0 + blockIdx.y;
  int j = threadIdx.x;                          // 64 threads, 1 wave
  int r = r_index[b];
  float acc = lb[j];
  for (int k = 0; k < 64; k++) acc = fmaf(rel_table[(size_t)r*64 + k], lw[(64 + k)*64 + j], acc);
  relb[j] = acc;
  float heur = acc;
  for (int k = 0; k < 64; k++) heur = fmaf(hs[b*64 + k], lw[k*64 + j], heur);
  float x = hs[b*64 + j] * heur;
  float o = 0.f;
  for (int half = 0; half < 2; half++){
    float a = b1[half*64 + j];
    for (int k = 0; k < 64; k++) a = fmaf(__shfl(x, k), w1[k*128 + half*64 + j], a);
    o = fmaf(fmaxf(a, 0.f), w2[half*64 + j], o);
  }
  o = waveSumF(o);
  if (j == 0) stF[7] = o + b2[0];
}

__global__ void k_inithidden(unsigned* WB, long sb, int b0,
                             const int* __restrict__ lastm, const float* __restrict__ ste,
                             const float* __restrict__ hs, const int* __restrict__ h_index){
  BBASE;
  float4* hidden = (float4*)(B + OFF_HID);
  const float4* ste4 = (const float4*)ste;
  const float4* hs4  = (const float4*)hs;
  int b = b0 + blockIdx.y;
  int idx = blockIdx.x * 256 + threadIdx.x;     // grid covers NN*16 exactly
  int n = idx >> 4, j = idx & 15;
  int h = h_index[b];
  float4 v = make_float4(0.f, 0.f, 0.f, 0.f);
  int lm = lastm[n];
  if (lm >= 0) v = ste4[(size_t)lm*16 + j];
  if (n == h)  v = hs4[b*16 + j];
  hidden[idx] = v;
}

__global__ void k_initscore(unsigned* WB, long sb, int b0,
                            const int* __restrict__ h_index, const float* __restrict__ gstF){
  BBASE;
  float* score = (float*)(B + OFF_SCORE);
  unsigned* st = B + OFF_ST;
  float* stF = (float*)st;
  int b = b0 + blockIdx.y;
  int i = blockIdx.x * 256 + threadIdx.x;
  if (i < NN) score[i] = (i == h_index[b]) ? stF[7] : gstF[6];
  if (i == 0){ st[0] = 0u; st[1] = KSEL; }
}

// ------------------------------ top-k machinery -----------------------------

// node histogram (unweighted): 2 leader rounds -> LDS hash -> single-plane flush
__global__ __launch_bounds__(256) void k_hist(unsigned* WB, long sb, int pass){
  BBASE;
  const unsigned* st = B + OFF_ST;
  const float* score = (const float*)(B + OFF_SCORE);
  unsigned* hist = B + ((pass == 1) ? OFF_HISTA : OFF_HISTB);
  __shared__ unsigned hkey[512];
  __shared__ unsigned hval[512];
  for (int t = threadIdx.x; t < 512; t += 256){ hkey[t] = 0xFFFFFFFFu; hval[t] = 0u; }
  __syncthreads();
  int i = blockIdx.x * 256 + threadIdx.x;
  unsigned bin = 0xFFFFFFFFu;
  if (i < NN){
    unsigned k = fkey(score[i]);
    if (pass == 1) bin = k >> 16;
    else if ((k >> 16) == (st[0] >> 16)) bin = k & 0xFFFFu;
  }
  bool active = (bin != 0xFFFFFFFFu);
  int lane = threadIdx.x & 63;
  #pragma unroll
  for (int r = 0; r < 2; r++){
    unsigned long long mask = __ballot((int)active);
    if (mask != 0ull){
      int leader = __ffsll(mask) - 1;
      unsigned lbin = (unsigned)__shfl((int)bin, leader);
      bool same = active && (bin == lbin);
      unsigned long long smask = __ballot((int)same);
      if (lane == leader) ldsHashAdd(hkey, hval, lbin, (unsigned)__popcll(smask));
      if (same) active = false;
    }
  }
  if (active) ldsHashAdd(hkey, hval, bin, 1u);
  __syncthreads();
  for (int t = threadIdx.x; t < 512; t += 256){
    unsigned vv = hval[t];
    if (vv) atomicAdd(hist + hkey[t], vv);
  }
}

// in-degree (from selected sources) accumulation into CURS + st reset;
// persists per-wave src-selected ballots into the dead ELIST region.
__global__ void k_indegW(unsigned* WB, long sb,
                         const int* __restrict__ esrc, const int* __restrict__ edst){
  BBASE;
  unsigned* st = B + OFF_ST;
  const unsigned* nsel = B + OFF_NSEL;
  unsigned* indeg = B + OFF_CURS;
  unsigned* sbal = B + OFF_ELIST;                // dead until selEdgesCompact
  int i = blockIdx.x * 256 + threadIdx.x;       // grid covers NEG exactly
  int wid = threadIdx.x >> 6, lane = threadIdx.x & 63;
  bool s = nsel[esrc[i]] != 0u;
  unsigned long long bal = __ballot((int)s);
  if (s) atomicAdd(indeg + edst[i], 1u);
  if (lane == 0){
    int gw = blockIdx.x * 4 + wid;
    sbal[2*gw]     = (unsigned)bal;
    sbal[2*gw + 1] = (unsigned)(bal >> 32);
  }
  if (i == 0){ st[0] = 0u; st[1] = ESEL; st[2] = 0u; st[3] = 0u; st[4] = 0u; st[5] = 0u; }
}

// weighted node histogram for the edge top-ESEL (weight = indeg)
__global__ __launch_bounds__(256) void k_histW(unsigned* WB, long sb, int pass){
  BBASE;
  const unsigned* st = B + OFF_ST;
  const unsigned* indeg = B + OFF_CURS;
  const float* score = (const float*)(B + OFF_SCORE);
  unsigned* hist = B + ((pass == 1) ? OFF_HISTA : OFF_HISTB);
  __shared__ unsigned hkey[512];
  __shared__ unsigned hval[512];
  for (int t = threadIdx.x; t < 512; t += 256){ hkey[t] = 0xFFFFFFFFu; hval[t] = 0u; }
  __syncthreads();
  int i = blockIdx.x * 256 + threadIdx.x;
  unsigned w = (i < NN) ? indeg[i] : 0u;
  if (w){
    unsigned k = fkey(score[i]);
    unsigned bin = 0xFFFFFFFFu;
    if (pass == 1) bin = k >> 16;
    else if ((k >> 16) == (st[0] >> 16)) bin = k & 0xFFFFu;
    if (bin != 0xFFFFFFFFu) ldsHashAdd(hkey, hval, bin, w);
  }
  __syncthreads();
  for (int t = threadIdx.x; t < 512; t += 256){
    unsigned vv = hval[t];
    if (vv) atomicAdd(hist + hkey[t], vv);
  }
}

// single block per batch: find digit containing the R-th largest; update st.
__global__ __launch_bounds__(1024) void k_pick16(unsigned* WB, long sb, int pass){
  BBASE;
  unsigned* st = B + OFF_ST;
  const unsigned* hist = B + ((pass == 1) ? OFF_HISTA : OFF_HISTB);
  __shared__ unsigned csum[1024];
  __shared__ unsigned sc[1024];
  int t = threadIdx.x;
  unsigned R = st[1];
  unsigned s = 0;
  {
    const unsigned* hp = hist + (unsigned)t * 64u;
    for (int b = 0; b < 64; b++) s += hp[b];
  }
  csum[t] = s; sc[t] = s; __syncthreads();
  for (int d = 1; d < 1024; d <<= 1){
    unsigned v = (t >= d) ? sc[t - d] : 0u;
    __syncthreads();
    sc[t] += v;
    __syncthreads();
  }
  unsigned total = sc[1023];
  unsigned above = total - sc[t];               // keys in higher chunks
  unsigned cs = csum[t];
  if (above < R && above + cs >= R){
    unsigned cum = above;
    for (int b = 63; b >= 0; b--){
      unsigned c = hist[(unsigned)(t*64 + b)];
      if (cum + c >= R){
        unsigned bstar = (unsigned)(t*64 + b);
        if (pass == 1) st[0] = bstar << 16; else st[0] = st[0] | bstar;
        st[1] = R - cum;
        break;
      }
      cum += c;
    }
  }
  if (t == 0 && total < R){                     // threshold lands in -inf bin
    if (pass == 1) st[0] = KEY_NEG_INF & 0xFFFF0000u;
    else           st[0] = st[0] | 0xFFFFu;
    st[1] = R - total;
  }
}

// per-block counts of (eq, gt) vs threshold; zeroes hist buffers AND dcnt.
// mode 0: node keys. mode 1: edge keys via srcsel ballots + eq/gt ballots saved.
__global__ __launch_bounds__(1024) void k_countEq(unsigned* WB, long sb, int mode, int n,
                                                  const int* __restrict__ esrc,
                                                  const int* __restrict__ edst){
  BBASE;
  unsigned* hz = B + OFF_HISTA;                  // A+B contiguous: 131072 u32
  for (unsigned j = blockIdx.x * 1024u + threadIdx.x; j < 131072u; j += gridDim.x * 1024u)
    hz[j] = 0u;
  unsigned* dcnt = B + OFF_DCNT;
  const unsigned* st = B + OFF_ST;
  const float* score = (const float*)(B + OFF_SCORE);
  unsigned* bcE = B + OFF_BC;
  unsigned* bcG = B + OFF_BC2;
  unsigned* balE = B + OFF_CSR;                  // eq/gt ballots (CSR dead here)
  unsigned* balG = B + OFF_BALG;
  int i = blockIdx.x * 1024 + threadIdx.x;
  if (i < NN) dcnt[i] = 0u;
  unsigned v = st[0];
  int wid = threadIdx.x >> 6, lane = threadIdx.x & 63;
  bool eq = false, gt = false;
  if (mode){
    const unsigned* sbal = B + OFF_ELIST;        // srcsel ballots from indegW
    int gw = blockIdx.x * 16 + wid;
    if (gw < NWAVE_E){
      unsigned long long sb64 = ((unsigned long long)sbal[2*gw + 1] << 32) | sbal[2*gw];
      bool ssel = (sb64 >> lane) & 1ull;
      unsigned k = KEY_NEG_INF;
      if (ssel) k = fkey(score[edst[i]]);
      eq = (k == v);
      gt = (k > v);
    }
  } else {
    unsigned k = 0u;
    if (i < n) k = fkey(score[i]);
    eq = (i < n) && (k == v);
    gt = (i < n) && (k > v);
  }
  unsigned long long ebal = __ballot((int)eq);
  unsigned long long gbal = __ballot((int)gt);
  __shared__ unsigned wshE[16];
  __shared__ unsigned wshG[16];
  if (mode && lane == 0){                        // persist ballots for compaction
    int gw = blockIdx.x * 16 + wid;
    balE[2*gw]     = (unsigned)ebal;
    balE[2*gw + 1] = (unsigned)(ebal >> 32);
    balG[2*gw]     = (unsigned)gbal;
    balG[2*gw + 1] = (unsigned)(gbal >> 32);
  }
  if (lane == 0){ wshE[wid] = (unsigned)__popcll(ebal); wshG[wid] = (unsigned)__popcll(gbal); }
  __syncthreads();
  if (threadIdx.x == 0){
    unsigned te = 0, tg = 0;
    for (int w = 0; w < 16; w++){ te += wshE[w]; tg += wshG[w]; }
    bcE[blockIdx.x] = te; bcG[blockIdx.x] = tg;
  }
}

__global__ __launch_bounds__(1024) void k_scanBlocks(unsigned* WB, long sb, int nbk){
  BBASE;
  unsigned* blockcnt = B + OFF_BC;
  __shared__ unsigned sc[2048];
  int t = threadIdx.x;
  unsigned a  = (t < nbk) ? blockcnt[t] : 0u;
  unsigned b2 = (1024 + t < nbk) ? blockcnt[1024 + t] : 0u;
  sc[t] = a; sc[1024 + t] = b2; __syncthreads();
  for (int d = 1; d < 2048; d <<= 1){
    unsigned v1 = (t >= d) ? sc[t - d] : 0u;
    unsigned v2 = (1024 + t >= d) ? sc[1024 + t - d] : 0u;
    __syncthreads();
    sc[t] += v1; sc[1024 + t] += v2;
    __syncthreads();
  }
  if (t < nbk) blockcnt[t] = sc[t] - a;             // exclusive
  if (1024 + t < nbk) blockcnt[1024 + t] = sc[1024 + t] - b2;
}

// dual scan (eq + gt) for edge compaction; also computes st[2], st[4]
__global__ __launch_bounds__(1024) void k_scanBlocks2(unsigned* WB, long sb, int nbk){
  BBASE;
  unsigned* st = B + OFF_ST;
  unsigned* bcE = B + OFF_BC;
  unsigned* bcG = B + OFF_BC2;
  __shared__ unsigned se[2048];
  __shared__ unsigned sg[2048];
  int t = threadIdx.x;
  unsigned e0 = (t < nbk) ? bcE[t] : 0u;
  unsigned e1 = (1024 + t < nbk) ? bcE[1024 + t] : 0u;
  unsigned g0 = (t < nbk) ? bcG[t] : 0u;
  unsigned g1 = (1024 + t < nbk) ? bcG[1024 + t] : 0u;
  se[t] = e0; se[1024 + t] = e1; sg[t] = g0; sg[1024 + t] = g1;
  __syncthreads();
  for (int d = 1; d < 2048; d <<= 1){
    unsigned a1 = (t >= d) ? se[t - d] : 0u;
    unsigned a2 = (1024 + t >= d) ? se[1024 + t - d] : 0u;
    unsigned c1 = (t >= d) ? sg[t - d] : 0u;
    unsigned c2 = (1024 + t >= d) ? sg[1024 + t - d] : 0u;
    __syncthreads();
    se[t] += a1; se[1024 + t] += a2; sg[t] += c1; sg[1024 + t] += c2;
    __syncthreads();
  }
  if (t < nbk) bcE[t] = se[t] - e0;
  if (1024 + t < nbk) bcE[1024 + t] = se[1024 + t] - e1;
  if (t < nbk) bcG[t] = sg[t] - g0;
  if (1024 + t < nbk) bcG[1024 + t] = sg[1024 + t] - g1;
  if (t == 0){
    unsigned gtTot = sg[2047];
    st[4] = gtTot;
    st[2] = gtTot + ((st[0] > KEY_NEG_INF) ? st[1] : 0u);  // R' <= eqTot always
  }
}

// node selection; also zeroes CURS (used as indeg accumulator next)
__global__ __launch_bounds__(1024) void k_selNodes(unsigned* WB, long sb){
  BBASE;
  const unsigned* st = B + OFF_ST;
  const unsigned* blockcnt = B + OFF_BC;
  const float* score = (const float*)(B + OFF_SCORE);
  unsigned* nsel = B + OFF_NSEL;
  unsigned* curs = B + OFF_CURS;
  int i = blockIdx.x * 1024 + threadIdx.x;
  if (i < NN) curs[i] = 0u;
  unsigned v = st[0], R = st[1];
  unsigned k = (i < NN) ? fkey(score[i]) : 0u;
  bool eq = (i < NN) && (k == v);
  unsigned long long bal = __ballot((int)eq);
  __shared__ unsigned wsh[16];
  int wid = threadIdx.x >> 6, lane = threadIdx.x & 63;
  if (lane == 0) wsh[wid] = (unsigned)__popcll(bal);
  __syncthreads();
  unsigned woff = 0;
  for (int w = 0; w < wid; w++) woff += wsh[w];
  unsigned lpre = (unsigned)__popcll(bal & ((1ull << lane) - 1ull));
  unsigned rank = blockcnt[blockIdx.x] + woff + lpre;
  if (i < NN) nsel[i] = (k > v || (eq && rank < R)) ? 1u : 0u;
}

// ballot-driven edge compaction (keys from stored ballots; deterministic);
// accumulates dcnt[dst] for taken edges (dcnt zeroed by k_countEq)
__global__ __launch_bounds__(1024) void k_selEdgesCompact(unsigned* WB, long sb,
                                                          const int* __restrict__ esrc,
                                                          const int* __restrict__ edst){
  BBASE;
  const unsigned* st = B + OFF_ST;
  const unsigned* bcE = B + OFF_BC;
  const unsigned* bcG = B + OFF_BC2;
  const unsigned* balE = B + OFF_CSR;
  const unsigned* balG = B + OFF_BALG;
  unsigned* elist = B + OFF_ELIST;
  unsigned* dcnt = B + OFF_DCNT;
  int i = blockIdx.x * 1024 + threadIdx.x;
  unsigned v = st[0], R = st[1], gtTot = st[4];
  int wid = threadIdx.x >> 6, lane = threadIdx.x & 63;
  int gw = blockIdx.x * 16 + wid;
  unsigned long long ebal = ((unsigned long long)balE[2*gw + 1] << 32) | balE[2*gw];
  unsigned long long gbal = ((unsigned long long)balG[2*gw + 1] << 32) | balG[2*gw];
  bool eq = (ebal >> lane) & 1ull;
  bool gt = (gbal >> lane) & 1ull;
  __shared__ unsigned wshE[16];
  __shared__ unsigned wshG[16];
  if (lane == 0){ wshE[wid] = (unsigned)__popcll(ebal); wshG[wid] = (unsigned)__popcll(gbal); }
  __syncthreads();
  unsigned eoff = 0, goff = 0;
  for (int w = 0; w < wid; w++){ eoff += wshE[w]; goff += wshG[w]; }
  unsigned long long ltm = (1ull << lane) - 1ull;
  if (gt){
    elist[bcG[blockIdx.x] + goff + (unsigned)__popcll(gbal & ltm)] = (unsigned)i;
    atomicAdd(dcnt + edst[i], 1u);
  }
  if (eq){
    unsigned rank = bcE[blockIdx.x] + eoff + (unsigned)__popcll(ebal & ltm);
    if (v > KEY_NEG_INF && rank < R){
      elist[gtTot + rank] = (unsigned)i;
      atomicAdd(dcnt + edst[i], 1u);
    }
  }
}

// ------------------------------- CSR build ----------------------------------

__global__ __launch_bounds__(1024) void k_blocksumsInt(unsigned* WB, long sb){
  BBASE;
  const unsigned* dcnt = B + OFF_DCNT;
  unsigned* blockcnt = B + OFF_BC;
  int i = blockIdx.x * 1024 + threadIdx.x;
  unsigned v = (i < NN) ? dcnt[i] : 0u;
  #pragma unroll
  for (int d = 1; d < 64; d <<= 1) v += (unsigned)__shfl_xor((int)v, d);
  __shared__ unsigned wsh[16];
  int wid = threadIdx.x >> 6, lane = threadIdx.x & 63;
  if (lane == 0) wsh[wid] = v;
  __syncthreads();
  if (threadIdx.x == 0){
    unsigned tot = 0;
    for (int w = 0; w < 16; w++) tot += wsh[w];
    blockcnt[blockIdx.x] = tot;
  }
}

// row starts + cursor + ACTIVE list + source snapshot (merged)
__global__ __launch_bounds__(1024) void k_rowSnap(unsigned* WB, long sb){
  BBASE;
  unsigned* st = B + OFF_ST;
  const unsigned* dcnt = B + OFF_DCNT;
  const unsigned* blockcnt = B + OFF_BC;
  unsigned* rowstart = B + OFF_ROWS;
  unsigned* curs = B + OFF_CURS;
  unsigned* actl = B + OFF_ACT;
  unsigned* srcmap = B + OFF_NSEL;
  const float* score = (const float*)(B + OFF_SCORE);
  const float* hidden = (const float*)(B + OFF_HID);
  float* srch = (float*)(B + OFF_SRCH);
  int i = blockIdx.x * 1024 + threadIdx.x;
  int wid = threadIdx.x >> 6, lane = threadIdx.x & 63;
  unsigned d = (i < NN) ? dcnt[i] : 0u;
  unsigned v = d;
  #pragma unroll
  for (int dl = 1; dl < 64; dl <<= 1){
    unsigned t2 = (unsigned)__shfl_up((int)v, dl);
    if (lane >= dl) v += t2;
  }
  bool act = (i < NN) && (d > 0u);
  unsigned long long abal = __ballot((int)act);
  __shared__ unsigned wsh[16];
  __shared__ unsigned awsh[16];
  __shared__ unsigned abase;
  if (lane == 63) wsh[wid] = v;
  if (lane == 0) awsh[wid] = (unsigned)__popcll(abal);
  __syncthreads();
  if (threadIdx.x == 0){
    unsigned tot = 0;
    for (int w = 0; w < 16; w++) tot += awsh[w];
    abase = atomicAdd(st + 3, tot);
  }
  unsigned woff = 0, aoff = 0;
  for (int w = 0; w < wid; w++){ woff += wsh[w]; aoff += awsh[w]; }
  __syncthreads();
  unsigned excl = blockcnt[blockIdx.x] + woff + (v - d);
  if (i < NN){ rowstart[i] = excl; curs[i] = excl; }
  if (act) actl[abase + aoff + (unsigned)__popcll(abal & ((1ull << lane) - 1ull))] = (unsigned)i;

  // ---- snap part: each wave handles its 64 nodes (disjoint arrays above)
  int base = i - lane;                        // wave's node base
  if (base >= NN) return;
  bool sel = (i < NN) && (srcmap[i] != 0u);
  unsigned long long bal = __ballot((int)sel);
  if (bal == 0ull) return;
  unsigned slotbase = 0;
  if (lane == 0) slotbase = atomicAdd(st + 5, (unsigned)__popcll(bal));
  slotbase = (unsigned)__shfl((int)slotbase, 0);
  unsigned long long m2 = bal;
  unsigned idx = 0;
  while (m2){
    int j = __ffsll(m2) - 1;
    m2 = m2 - (m2 bitand (0ull - m2));        // clear lowest set bit (entity-safe)
    int node = base + j;
    unsigned slot = slotbase + idx; idx++;
    if (lane == 0) srcmap[node] = slot;
    float g = 1.f / (1.f + expf(-score[node]));   // same formula as before
    srch[(size_t)slot*64 + lane] = g * hidden[(size_t)node*64 + lane];
  }
}

// scatter packed (slot<<10)|etype into CSR (needs srcmap from k_rowSnap)
__global__ void k_scatter(unsigned* WB, long sb, const int* __restrict__ esrc,
                          const int* __restrict__ edst, const int* __restrict__ etype){
  BBASE;
  const unsigned* st = B + OFF_ST;
  const unsigned* elist = B + OFF_ELIST;
  const unsigned* srcmap = B + OFF_NSEL;
  unsigned* curs = B + OFF_CURS;
  unsigned* csr = B + OFF_CSR;
  unsigned i = blockIdx.x * 256 + threadIdx.x;
  if (i < st[2]){
    unsigned e = elist[i];
    unsigned slot = srcmap[esrc[e]];
    unsigned pk = (slot << 10) | (unsigned)etype[e];
    unsigned pos = atomicAdd(curs + edst[e], 1u);
    csr[pos] = pk;
  }
}

// --------------------- fused aggregation + PNA update -----------------------
// R30 aggpna (unchanged): lane=node + SGPR-weight matmul; 16 KB LDS single
// plane; single gather with bulk metadata prefetch + group-of-4 first-chunk
// csr prefetch. Bit-exact.

__global__ __launch_bounds__(256) void k_aggpna(unsigned* WB, long sb,
    const float* __restrict__ relw, const float* __restrict__ pw,
    const float* __restrict__ pb, const float* __restrict__ gstF, int l){
  BBASE;
  const unsigned* st = B + OFF_ST;
  const unsigned* actl = B + OFF_ACT;
  const unsigned* dcnt = B + OFF_DCNT;
  const unsigned* rows = B + OFF_ROWS;
  const unsigned* csr = B + OFF_CSR;
  const float* srch = (const float*)(B + OFF_SRCH);
  float* hidden = (float*)(B + OFF_HID);
  const float* relw_l = relw + (size_t)l * NR2 * 64;
  const float* pw_l = pw + (size_t)l * 768 * 64;

  __shared__ float aggL[64 * 64];               // ONE plane, 16 KB

  int lane = threadIdx.x & 63;
  int w = threadIdx.x >> 6;
  unsigned nact = st[3];
  unsigned nbase = (unsigned)blockIdx.x * 64u;
  if (nbase >= nact) return;                    // block-uniform exit
  float dmean = gstF[5];

  // persistent matmul state (lane = node)
  unsigned slotM = nbase + (unsigned)lane;
  int nodeM = (slotM < nact) ? (int)actl[slotM] : -1;
  float dvM = (nodeM >= 0) ? (float)dcnt[nodeM] : 0.f;
  float logd = logf(dvM + 1.f);
  float ampv = logd / dmean;
  float attv = dmean / fmaxf(logd, 1e-6f);
  int jbase = __builtin_amdgcn_readfirstlane((int)(threadIdx.x >> 6)) * 16;
  float acc[16];
  #pragma unroll
  for (int jj = 0; jj < 16; jj++) acc[jj] = pb[(size_t)l*64 + jbase + jj];

  // ---- bulk metadata prefetch: the wave's 16 nodes (wave-uniform addrs)
  int nodeG[16]; unsigned cntG[16], rsG[16];
  #pragma unroll
  for (int i = 0; i < 16; i++){
    unsigned slot = nbase + (unsigned)(w * 16 + i);
    nodeG[i] = (slot < nact) ? (int)actl[slot] : -1;
  }
  #pragma unroll
  for (int i = 0; i < 16; i++){
    cntG[i] = (nodeG[i] >= 0) ? dcnt[nodeG[i]] : 0u;
    rsG[i]  = (nodeG[i] >= 0) ? rows[nodeG[i]] : 0u;
  }

  // ---- SINGLE gather pass, group-of-4 first-chunk prefetch.
  float mxS[16], mnS[16], sdS[16];
  #pragma unroll
  for (int g = 0; g < 4; g++){
    // prefetch first csr chunk (clamped, identical to ii=0 indices)
    unsigned pkA[4], pkB[4], pkC[4], pkD[4];
    #pragma unroll
    for (int q = 0; q < 4; q++){
      int i = g*4 + q;
      unsigned cnt = cntG[i], rs = rsG[i];
      bool vld = (nodeG[i] >= 0);
      unsigned c1 = (1u < cnt) ? 1u : 0u;
      unsigned c2 = (2u < cnt) ? 2u : 0u;
      unsigned c3 = (3u < cnt) ? 3u : 0u;
      pkA[q] = vld ? csr[rs]      : 0u;
      pkB[q] = vld ? csr[rs + c1] : 0u;
      pkC[q] = vld ? csr[rs + c2] : 0u;
      pkD[q] = vld ? csr[rs + c3] : 0u;
    }
    #pragma unroll
    for (int q = 0; q < 4; q++){
      int i = g*4 + q;
      int nloc = w * 16 + i;
      float pmean = 0.f;
      mxS[i] = 0.f; mnS[i] = 0.f; sdS[i] = 0.f;
      if (nodeG[i] >= 0){
        unsigned cnt = cntG[i], rs = rsG[i];
        float sm_ = 0.f, sq_ = 0.f;
        float mx_ = -__builtin_huge_valf(), mn_ = __builtin_huge_valf();
        // ---- chunk 0 from prefetch (guards == original ii=0 guards)
        {
          unsigned pk0 = pkA[q], pk1 = pkB[q], pk2 = pkC[q], pk3 = pkD[q];
          float s0 = srch[(size_t)(pk0 >> 10)*64 + lane];
          float r0 = relw_l[(size_t)(pk0 & 1023u)*64 + lane];
          float s1 = srch[(size_t)(pk1 >> 10)*64 + lane];
          float r1 = relw_l[(size_t)(pk1 & 1023u)*64 + lane];
          float s2 = srch[(size_t)(pk2 >> 10)*64 + lane];
          float r2 = relw_l[(size_t)(pk2 & 1023u)*64 + lane];
          float s3 = srch[(size_t)(pk3 >> 10)*64 + lane];
          float r3 = relw_l[(size_t)(pk3 & 1023u)*64 + lane];
          float m = s0 * r0;
          sm_ += m; sq_ = fmaf(m, m, sq_); mx_ = fmaxf(mx_, m); mn_ = fminf(mn_, m);
          if (1u < cnt){
            m = s1 * r1;
            sm_ += m; sq_ = fmaf(m, m, sq_); mx_ = fmaxf(mx_, m); mn_ = fminf(mn_, m);
          }
          if (2u < cnt){
            m = s2 * r2;
            sm_ += m; sq_ = fmaf(m, m, sq_); mx_ = fmaxf(mx_, m); mn_ = fminf(mn_, m);
          }
          if (3u < cnt){
            m = s3 * r3;
            sm_ += m; sq_ = fmaf(m, m, sq_); mx_ = fmaxf(mx_, m); mn_ = fminf(mn_, m);
          }
        }
        // ---- remaining chunks (rare: avg degree ~3.3)
        for (unsigned ii = 4; ii < cnt; ii += 4u){
          unsigned i1 = (ii + 1u < cnt) ? ii + 1u : ii;
          unsigned i2 = (ii + 2u < cnt) ? ii + 2u : ii;
          unsigned i3 = (ii + 3u < cnt) ? ii + 3u : ii;
          unsigned pk0 = csr[rs + ii];
          unsigned pk1 = csr[rs + i1];
          unsigned pk2 = csr[rs + i2];
          unsigned pk3 = csr[rs + i3];
          float s0 = srch[(size_t)(pk0 >> 10)*64 + lane];
          float r0 = relw_l[(size_t)(pk0 & 1023u)*64 + lane];
          float s1 = srch[(size_t)(pk1 >> 10)*64 + lane];
          float r1 = relw_l[(size_t)(pk1 & 1023u)*64 + lane];
          float s2 = srch[(size_t)(pk2 >> 10)*64 + lane];
          float r2 = relw_l[(size_t)(pk2 & 1023u)*64 + lane];
          float s3 = srch[(size_t)(pk3 >> 10)*64 + lane];
          float r3 = relw_l[(size_t)(pk3 & 1023u)*64 + lane];
          float m = s0 * r0;
          sm_ += m; sq_ = fmaf(m, m, sq_); mx_ = fmaxf(mx_, m); mn_ = fminf(mn_, m);
          if (ii + 1u < cnt){
            m = s1 * r1;
            sm_ += m; sq_ = fmaf(m, m, sq_); mx_ = fmaxf(mx_, m); mn_ = fminf(mn_, m);
          }
          if (ii + 2u < cnt){
            m = s2 * r2;
            sm_ += m; sq_ = fmaf(m, m, sq_); mx_ = fmaxf(mx_, m); mn_ = fminf(mn_, m);
          }
          if (ii + 3u < cnt){
            m = s3 * r3;
            sm_ += m; sq_ = fmaf(m, m, sq_); mx_ = fmaxf(mx_, m); mn_ = fminf(mn_, m);
          }
        }
        float dv = (float)cnt;
        float degc = fmaxf(dv, 1.f);
        float me = sm_ / degc;
        pmean = me;
        mxS[i] = mx_;
        mnS[i] = mn_;
        sdS[i] = sqrtf(fmaxf(sq_ / degc - me*me, 0.f) + 1e-6f);
      }
      aggL[lane*64 + (nloc ^ lane)] = pmean;    // XOR swizzle (2-way banks)
    }
  }

  for (int p = 0; p < 4; p++){
    if (p){
      __syncthreads();                          // prior phase's matmul reads done
      #pragma unroll
      for (int i = 0; i < 16; i++){
        int nloc = w * 16 + i;
        float v = (p == 1) ? mxS[i] : ((p == 2) ? mnS[i] : sdS[i]);
        aggL[lane*64 + (nloc ^ lane)] = v;
      }
    }
    __syncthreads();
    // ---- matmul: c = p*3 .. p*3+2 from the single plane
    for (int cc = 0; cc < 3; cc++){
      int c = p*3 + cc;
      float sc = (cc == 0) ? 1.f : ((cc == 1) ? ampv : attv);
      const float* wc = pw_l + (size_t)c*64*64 + jbase;   // uniform -> s_load
      #pragma unroll 4
      for (int k = 0; k < 64; k++){
        float fv = aggL[k*64 + (lane ^ k)] * sc;          // 2-way banks
        const float* wp = wc + (size_t)k*64;
        #pragma unroll
        for (int jj = 0; jj < 16; jj++)
          acc[jj] = fmaf(fv, wp[jj], acc[jj]);            // SGPR weight operand
      }
    }
  }
  if (nodeM >= 0){
    float* hp = hidden + (size_t)nodeM*64 + jbase;
    #pragma unroll
    for (int q = 0; q < 4; q++){
      float4 h = *(float4*)(hp + q*4);
      h.x += acc[q*4+0]; h.y += acc[q*4+1]; h.z += acc[q*4+2]; h.w += acc[q*4+3];
      *(float4*)(hp + q*4) = h;
    }
  }
}

// ------------------------- rescore active nodes -----------------------------
// R30 scoreK (unchanged): lane=node + SGPR-weight, node prefetch in G phase.

__global__ __launch_bounds__(256) void k_scoreK(unsigned* WB, long sb,
    const float* __restrict__ lw, const float* __restrict__ w1,
    const float* __restrict__ b1, const float* __restrict__ w2,
    const float* __restrict__ b2){
  BBASE;
  unsigned* st = B + OFF_ST;
  if (blockIdx.x == 0 && threadIdx.x == 0){ st[0] = 0u; st[1] = KSEL; }  // next node topk
  const unsigned* actl = B + OFF_ACT;
  const float* hidden = (const float*)(B + OFF_HID);
  const float* relb = (const float*)(B + OFF_RELB);
  float* score = (float*)(B + OFF_SCORE);

  __shared__ float P0[64 * 64];                 // H, later P (pre-combined out)
  __shared__ float P1[64 * 64];                 // X

  int lane = threadIdx.x & 63;
  int w = threadIdx.x >> 6;
  unsigned nact = st[3];
  unsigned nbase = (unsigned)blockIdx.x * 64u;
  if (nbase >= nact) return;                    // block-uniform exit

  // ---- G: node prefetch, then hidden tile -> H[k][n^k] (lane = k)
  int nodeG[16];
  #pragma unroll
  for (int i = 0; i < 16; i++){
    unsigned slot = nbase + (unsigned)(w * 16 + i);
    nodeG[i] = (slot < nact) ? (int)actl[slot] : -1;
  }
  #pragma unroll
  for (int i = 0; i < 16; i++){
    int nloc = w * 16 + i;
    float hv = (nodeG[i] >= 0) ? hidden[(size_t)nodeG[i]*64 + lane] : 0.f;
    P0[lane*64 + (nloc ^ lane)] = hv;
  }
  __syncthreads();

  // ---- P1 phase: lane = node; wave w owns j in [16w, 16w+16)
  int jb = __builtin_amdgcn_readfirstlane(w) * 16;
  float heur[16];
  #pragma unroll
  for (int i = 0; i < 16; i++) heur[i] = relb[jb + i];
  #pragma unroll 4
  for (int k = 0; k < 64; k++){
    float hk = P0[k*64 + (lane ^ k)];
    const float* lwk = lw + k*64 + jb;          // uniform -> s_load
    #pragma unroll
    for (int i = 0; i < 16; i++) heur[i] = fmaf(hk, lwk[i], heur[i]);
  }
  #pragma unroll
  for (int i = 0; i < 16; i++){
    int j = jb + i;
    float hj = P0[j*64 + (lane ^ j)];
    P1[j*64 + (lane ^ j)] = hj * heur[i];       // x = hid * heur
  }
  __syncthreads();                              // X complete; H reads done

  // ---- P2 phase: lane = node; wave w owns m in {jb..jb+15} u {64+jb..}
  float alo[16], ahi[16];
  #pragma unroll
  for (int mm = 0; mm < 16; mm++){ alo[mm] = b1[jb + mm]; ahi[mm] = b1[64 + jb + mm]; }
  #pragma unroll 4
  for (int j = 0; j < 64; j++){
    float xj = P1[j*64 + (lane ^ j)];
    const float* w1j = w1 + j*128;              // uniform -> s_load
    #pragma unroll
    for (int mm = 0; mm < 16; mm++){
      alo[mm] = fmaf(xj, w1j[jb + mm], alo[mm]);
      ahi[mm] = fmaf(xj, w1j[64 + jb + mm], ahi[mm]);
    }
  }
  // pre-combine in the ORIGINAL per-lane two-term order -> P rows jb..jb+15
  #pragma unroll
  for (int mm = 0; mm < 16; mm++){
    int j = jb + mm;
    float p = fmaf(fmaxf(alo[mm], 0.f), w2[j], 0.f);
    p = fmaf(fmaxf(ahi[mm], 0.f), w2[64 + j], p);
    P0[j*64 + (lane ^ j)] = p;
  }
  __syncthreads();

  // ---- P3 phase: lane = j; original balanced butterfly per node
  float b2v = b2[0];
  for (int i = 0; i < 16; i++){
    int nloc = w * 16 + i;
    unsigned slot = nbase + (unsigned)nloc;
    float p = P0[lane*64 + (nloc ^ lane)];
    float r = waveSumF(p);
    if (lane == 0 && slot < nact) score[(int)actl[slot]] = r + b2v;
  }
}

__global__ void k_out(unsigned* WB, long sb, int b0,
                      const int* __restrict__ t_index, float* __restrict__ out){
  BBASE;
  const float* score = (const float*)(B + OFF_SCORE);
  int b = b0 + blockIdx.y;
  int t = threadIdx.x;
  if (t < NTC) out[b*NTC + t] = score[t_index[b*NTC + t]];
}

// ------------------------------- launcher -----------------------------------

extern "C" void kernel_launch(void* const* d_in, const int* in_sizes, int n_in,
                              void* d_out, int out_size, void* d_ws, size_t ws_size,
                              hipStream_t stream){
  (void)in_sizes; (void)n_in; (void)out_size;
  const int*   h_index  = (const int*)d_in[0];
  const int*   r_index  = (const int*)d_in[1];
  const int*   t_index  = (const int*)d_in[2];
  const int*   all_idx  = (const int*)d_in[3];
  const int*   esrc     = (const int*)d_in[4];
  const int*   edst     = (const int*)d_in[5];
  const int*   etype    = (const int*)d_in[6];
  const float* hs       = (const float*)d_in[7];
  const float* ste      = (const float*)d_in[8];
  const float* rel_tab  = (const float*)d_in[9];
  const float* lw       = (const float*)d_in[10];
  const float* lb       = (const float*)d_in[11];
  const float* w1       = (const float*)d_in[12];
  const float* b1       = (const float*)d_in[13];
  const float* w2       = (const float*)d_in[14];
  const float* b2       = (const float*)d_in[15];
  const float* relw     = (const float*)d_in[16];
  const float* pna_w    = (const float*)d_in[17];
  const float* pna_b    = (const float*)d_in[18];
  float* out = (float*)d_out;

  unsigned* W = (unsigned*)d_ws;
  int*      LASTM = (int*)W;                    // 50000
  unsigned* DEGF  = W + 50000;                  // 50000
  float*    GSTF  = (float*)(W + 100000);       // 64
  unsigned* WB    = W + 100064;                 // batch blocks

  size_t needB = (size_t)(100064 + 4*(size_t)SBLK) * 4u;
  int nb; long sb; int nseq;
  if (ws_size >= needB){ nb = 4; sb = SBLK; nseq = 1; }
  else                 { nb = 1; sb = 0;    nseq = 4; }

  (void)hipMemsetAsync(W + 100000, 0, 64 * 4, stream);          // GSTF
  (void)hipMemsetAsync(LASTM, 0xFF, NN * 4, stream);
  (void)hipMemsetAsync(DEGF, 0, NN * 4, stream);
  for (int q = 0; q < nb; q++)
    (void)hipMemsetAsync(WB + (size_t)q*SBLK + OFF_HISTA, 0, 131072 * 4, stream);

  const int GB_E256  = (NEG + 255) / 256;       // 6250
  const int GB_N256  = (NN + 255) / 256;        // 196
  const int GB_N1024 = (NN + 1023) / 1024;      // 49
  const int GB_E1024 = (NEG + 1023) / 1024;     // 1563
  const int GB_H4    = (NN * 16) / 256;         // 3125 (float4 rows)
  const int GB_A2    = (NN + 63) / 64;          // 782 (64 nodes per WG)
  const int GB_ES    = (int)(ESEL / 256);       // 625

  k_lastm<<<(NMI + 255) / 256, 256, 0, stream>>>(all_idx, LASTM);
  k_degfull<<<GB_E256, 256, 0, stream>>>(esrc, DEGF);
  k_dsum<<<GB_N256, 256, 0, stream>>>(DEGF, GSTF);
  k_finalize<<<1, 1, 0, stream>>>(GSTF, b1, w2, b2);

  for (int q = 0; q < nseq; q++){
    int b0 = (nb == 4) ? 0 : q;
    k_relb<<<dim3(1, nb), 64, 0, stream>>>(WB, sb, b0, r_index, hs, rel_tab, lw, lb, w1, b1, w2, b2);
    k_inithidden<<<dim3(GB_H4, nb), 256, 0, stream>>>(WB, sb, b0, LASTM, ste, hs, h_index);
    k_initscore<<<dim3(GB_N256, nb), 256, 0, stream>>>(WB, sb, b0, h_index, GSTF);

    for (int l = 0; l < 3; l++){
      // ---- node top-K
      k_hist<<<dim3(GB_N256, nb), 256, 0, stream>>>(WB, sb, 1);
      k_pick16<<<dim3(1, nb), 1024, 0, stream>>>(WB, sb, 1);
      k_hist<<<dim3(GB_N256, nb), 256, 0, stream>>>(WB, sb, 0);
      k_pick16<<<dim3(1, nb), 1024, 0, stream>>>(WB, sb, 0);
      k_countEq<<<dim3(GB_N1024, nb), 1024, 0, stream>>>(WB, sb, 0, NN, esrc, edst);
      k_scanBlocks<<<dim3(1, nb), 1024, 0, stream>>>(WB, sb, GB_N1024);
      k_selNodes<<<dim3(GB_N1024, nb), 1024, 0, stream>>>(WB, sb);      // + zeroes CURS
      // ---- edge top-ESEL as weighted node top-k
      k_indegW<<<dim3(GB_E256, nb), 256, 0, stream>>>(WB, sb, esrc, edst);
      k_histW<<<dim3(GB_N256, nb), 256, 0, stream>>>(WB, sb, 1);
      k_pick16<<<dim3(1, nb), 1024, 0, stream>>>(WB, sb, 1);
      k_histW<<<dim3(GB_N256, nb), 256, 0, stream>>>(WB, sb, 0);
      k_pick16<<<dim3(1, nb), 1024, 0, stream>>>(WB, sb, 0);
      k_countEq<<<dim3(GB_E1024, nb), 1024, 0, stream>>>(WB, sb, 1, NEG, esrc, edst);
      k_scanBlocks2<<<dim3(1, nb), 1024, 0, stream>>>(WB, sb, GB_E1024);
      k_selEdgesCompact<<<dim3(GB_E1024, nb), 1024, 0, stream>>>(WB, sb, esrc, edst);
      // ---- CSR rows + active compaction + snapshot (merged) + scatter
      k_blocksumsInt<<<dim3(GB_N1024, nb), 1024, 0, stream>>>(WB, sb);
      k_scanBlocks<<<dim3(1, nb), 1024, 0, stream>>>(WB, sb, GB_N1024);
      k_rowSnap<<<dim3(GB_N1024, nb), 1024, 0, stream>>>(WB, sb);
      k_scatter<<<dim3(GB_ES, nb), 256, 0, stream>>>(WB, sb, esrc, edst, etype);
      // ---- fused aggregate + PNA update, then rescore
      k_aggpna<<<dim3(GB_A2, nb), 256, 0, stream>>>(WB, sb, relw, pna_w, pna_b, GSTF, l);
      k_scoreK<<<dim3(GB_A2, nb), 256, 0, stream>>>(WB, sb, lw, w1, b1, w2, b2);
    }
    k_out<<<dim3(1, nb), 32, 0, stream>>>(WB, sb, b0, t_index, out);
  }
}